// Round 12
// baseline (45.840 us; speedup 1.0000x reference)
//
#include <hip/hip_runtime.h>
#include <hip/hip_fp16.h>
#include <cstddef>

#define DIM 2048
#define NTOK 8192
#define NEUMANN_ITERS 6

// Math (validated rounds 1-11):
//   omega = P Q^T, P=[U|V], Q=[sV|-sU], G = Q^T P  (16x16)
//   Y = (I - G/2)^{-1}(I + G/2)  via Neumann-Horner: Y <- B + 0.5*G*Y, B=I+G/2
//   out = x + sum_k c[k] P[:,k],
//   c[k] = 0.5*s* sum_j Z[k][j] b[j],  Z = I + Y,
//     b[j<8] = av[j], b[j>=8] = -au[j-8];  au = x.U, av = x.V
//
// Structural lessons baked in:
//  - No 1-block dispatches (rounds 2/4: ~100 us stall floor).
//  - No per-block redundant gram loop (round 5: ~380 us).
//  - No min-waves clause in launch_bounds (round 6: VGPR cap -> spill).
//  - UV staged once per block in LDS as f16 pairs (rounds 9/11).
//  - Round 11: latency-bound (VALU 26%, hbm 36%, occ 30%); LDS caps TLP at
//    16 waves/CU. THIS round: ILP fixes — float4 x (16B/lane), phase-2
//    chain depth 16 -> 4-8 via 4 independent half2 accumulators.
//  - cvt_pkrtz returns __fp16 ext_vector(2): bit_cast everywhere.
//  - No runtime indexing of register arrays.

typedef _Float16 h2 __attribute__((ext_vector_type(2)));

__device__ __forceinline__ unsigned pkh(float lo, float hi) {
  auto p = __builtin_amdgcn_cvt_pkrtz(lo, hi);   // v_cvt_pkrtz_f16_f32
  return __builtin_bit_cast(unsigned, p);
}
__device__ __forceinline__ h2 cvt2h(float lo, float hi) {
  auto p = __builtin_amdgcn_cvt_pkrtz(lo, hi);
  return __builtin_bit_cast(h2, p);
}

template <int CTRL>
__device__ __forceinline__ float dpp_add(float v) {
  const int t =
      __builtin_amdgcn_update_dpp(0, __float_as_int(v), CTRL, 0xf, 0xf, true);
  return v + __int_as_float(t);
}
__device__ __forceinline__ float wave_red(float v) {
  v = dpp_add<0xB1>(v);    // quad_perm [1,0,3,2]  (xor 1)
  v = dpp_add<0x4E>(v);    // quad_perm [2,3,0,1]  (xor 2)
  v = dpp_add<0x141>(v);   // row_half_mirror      (pairs halves of 8)
  v = dpp_add<0x140>(v);   // row_mirror           (pairs halves of 16)
  v += __shfl_xor(v, 16, 64);
  v += __shfl_xor(v, 32, 64);
  return v;
}

// ---------------------------------------------------------------------------
// 1) Gram: one block per entry e=(q,i,j); 256 threads reduce over d=2048.
// ---------------------------------------------------------------------------
__global__ __launch_bounds__(256) void rora_gram(
    const float* __restrict__ U, const float* __restrict__ V,
    float* __restrict__ prod) {
  const int e = blockIdx.x;            // 0..191
  const int q = e >> 6;                // 0: U^T U, 1: U^T V, 2: V^T V
  const int i = (e >> 3) & 7, j = e & 7;
  const float* A = (q == 2) ? V : U;
  const float* B = (q == 0) ? U : V;
  const int t = threadIdx.x;
  float acc = 0.f;
#pragma unroll
  for (int s = 0; s < 8; ++s) {
    const int d = s * 256 + t;
    acc = fmaf(A[d * 8 + i], B[d * 8 + j], acc);
  }
#pragma unroll
  for (int m = 1; m < 64; m <<= 1) acc += __shfl_xor(acc, m, 64);
  __shared__ float wsum[4];
  if ((t & 63) == 0) wsum[t >> 6] = acc;
  __syncthreads();
  if (t == 0) prod[e] = (wsum[0] + wsum[1]) + (wsum[2] + wsum[3]);
}

// ---------------------------------------------------------------------------
// 2) Fused: UV->LDS f16-pair staging + 16x16 setup + streaming main.
//    512 threads = 8 waves x 2 rows; grid 512; 2 blocks/CU.
//    uvQ[q][P].comp(m) = half2( W[2P][4q+m], W[2P+1][4q+m] ),
//      slots: q=0 U cols 0-3, q=1 U cols 4-7, q=2 V cols 0-3, q=3 V cols 4-7.
// ---------------------------------------------------------------------------
__global__ __launch_bounds__(512) void rora_fused(
    const float* __restrict__ x, const float* __restrict__ U,
    const float* __restrict__ V, const float* __restrict__ gate,
    const float* __restrict__ prod, float* __restrict__ out) {
  __shared__ uint4 uvQ[4][DIM / 2];   // 64 KB
  __shared__ float prodS[192];        // [q*64 + i*8 + j]
  __shared__ float Gs[16][17];
  __shared__ float Bm[16][17];
  __shared__ float Ya[16][17];
  __shared__ float Yb[16][17];
  const int t = threadIdx.x;

  // ---- stage U,V -> LDS as f16 d-pairs ----
  {
    const float4* U4 = (const float4*)U;
    const float4* V4 = (const float4*)V;
#pragma unroll
    for (int rep = 0; rep < 2; ++rep) {
      const int P = rep * 512 + t;    // d-pair (2P, 2P+1)
      const float4 a0 = U4[4 * P + 0], a1 = U4[4 * P + 1];  // U[2P][0..7]
      const float4 a2 = U4[4 * P + 2], a3 = U4[4 * P + 3];  // U[2P+1][0..7]
      const float4 b0 = V4[4 * P + 0], b1 = V4[4 * P + 1];
      const float4 b2 = V4[4 * P + 2], b3 = V4[4 * P + 3];
      uvQ[0][P] = make_uint4(pkh(a0.x, a2.x), pkh(a0.y, a2.y),
                             pkh(a0.z, a2.z), pkh(a0.w, a2.w));
      uvQ[1][P] = make_uint4(pkh(a1.x, a3.x), pkh(a1.y, a3.y),
                             pkh(a1.z, a3.z), pkh(a1.w, a3.w));
      uvQ[2][P] = make_uint4(pkh(b0.x, b2.x), pkh(b0.y, b2.y),
                             pkh(b0.z, b2.z), pkh(b0.w, b2.w));
      uvQ[3][P] = make_uint4(pkh(b1.x, b3.x), pkh(b1.y, b3.y),
                             pkh(b1.z, b3.z), pkh(b1.w, b3.w));
    }
  }

  // ---- 16x16 setup (f32, from ws gram products) ----
  if (t < 192) prodS[t] = prod[t];
  __syncthreads();
  const float sg = 1.f / (1.f + expf(-gate[0]));
  if (t < 256) {
    const int r = t >> 4, c = t & 15;
    float g;
    if (r < 8) g = (c < 8) ? sg * prodS[64 + c * 8 + r]              // (V^T U)
                           : sg * prodS[128 + r * 8 + (c - 8)];      // (V^T V)
    else       g = (c < 8) ? -sg * prodS[(r - 8) * 8 + c]            // -(U^T U)
                           : -sg * prodS[64 + (r - 8) * 8 + (c - 8)];
    const float b = ((r == c) ? 1.f : 0.f) + 0.5f * g;
    Gs[r][c] = g;
    Bm[r][c] = b;
    Ya[r][c] = b;
  }
  __syncthreads();
#pragma unroll
  for (int m = 0; m < NEUMANN_ITERS; ++m) {   // ends in Ya (last m odd)
    if (t < 256) {
      const int r = t >> 4, c = t & 15;
      const float (*Yp)[17] = (m & 1) ? Yb : Ya;
      float (*Yn)[17] = (m & 1) ? Ya : Yb;
      float acc = Bm[r][c];
#pragma unroll
      for (int j = 0; j < 16; ++j)
        acc = fmaf(0.5f * Gs[r][j], Yp[j][c], acc);
      Yn[r][c] = acc;
    }
    __syncthreads();   // final barrier also orders uvQ staging before reads
  }

  // ---- main: 8 waves, 2 rows/wave; lane owns d-quads iq = i*64+lane ----
  const int wv = t >> 6, lane = t & 63;
  const int row0 = blockIdx.x * 16 + wv * 2;
  const float4* x4A = (const float4*)(x + (size_t)row0 * DIM);
  const float4* x4B = x4A + DIM / 4;

  float a0[16], a1[16];
#pragma unroll
  for (int k = 0; k < 16; ++k) { a0[k] = 0.f; a1[k] = 0.f; }

#if __has_builtin(__builtin_amdgcn_fdot2)
#define P1STEP(acc, xp, w) \
  acc = __builtin_amdgcn_fdot2(xp, __builtin_bit_cast(h2, w), acc, false)
#else
#define P1STEP(acc, xp, w)                                             \
  {                                                                    \
    const __half2 _u = __builtin_bit_cast(__half2, w);                 \
    const float _x0 = (float)((__builtin_bit_cast(h2, xp))[0]);        \
    const float _x1 = (float)((__builtin_bit_cast(h2, xp))[1]);        \
    acc = fmaf(_x0, __low2float(_u), fmaf(_x1, __high2float(_u), acc)); \
  }
#endif
// one k-quad (4 columns) from word-pair (W0=pair0, W1=pair1)
#define K4(arr, base, W0, W1, xp0, xp1)                 \
  P1STEP(arr[base + 0], xp0, W0.x);                     \
  P1STEP(arr[base + 0], xp1, W1.x);                     \
  P1STEP(arr[base + 1], xp0, W0.y);                     \
  P1STEP(arr[base + 1], xp1, W1.y);                     \
  P1STEP(arr[base + 2], xp0, W0.z);                     \
  P1STEP(arr[base + 2], xp1, W1.z);                     \
  P1STEP(arr[base + 3], xp0, W0.w);                     \
  P1STEP(arr[base + 3], xp1, W1.w);

  // phase 1: a = [x.U | x.V]; float4 covers pairs P0=2iq, P1=2iq+1
#pragma unroll 2
  for (int i = 0; i < 8; ++i) {
    const int iq = i * 64 + lane;
    const float4 xA = x4A[iq], xB = x4B[iq];
    const uint4 A0 = uvQ[0][2 * iq], A1 = uvQ[0][2 * iq + 1];
    const uint4 B0 = uvQ[1][2 * iq], B1 = uvQ[1][2 * iq + 1];
    const uint4 C0 = uvQ[2][2 * iq], C1 = uvQ[2][2 * iq + 1];
    const uint4 D0 = uvQ[3][2 * iq], D1 = uvQ[3][2 * iq + 1];
    const h2 xa0 = cvt2h(xA.x, xA.y), xa1 = cvt2h(xA.z, xA.w);
    const h2 xb0 = cvt2h(xB.x, xB.y), xb1 = cvt2h(xB.z, xB.w);
    K4(a0, 0, A0, A1, xa0, xa1);
    K4(a0, 4, B0, B1, xa0, xa1);
    K4(a0, 8, C0, C1, xa0, xa1);
    K4(a0, 12, D0, D1, xa0, xa1);
    K4(a1, 0, A0, A1, xb0, xb1);
    K4(a1, 4, B0, B1, xb0, xb1);
    K4(a1, 8, C0, C1, xb0, xb1);
    K4(a1, 12, D0, D1, xb0, xb1);
  }
#undef K4
#undef P1STEP

  // butterfly: 4 DPP VALU levels + 2 shuffles per value
#pragma unroll
  for (int k = 0; k < 16; ++k) {
    a0[k] = wave_red(a0[k]);
    a1[k] = wave_red(a1[k]);
  }

  // c[k] = 0.5*s * sum_j Z[k][j] b[j]; lane kk=lane&15 computes row kk.
  __half2 ch0[16], ch1[16];
  {
    const int kk = lane & 15;
    float zrow[16];
#pragma unroll
    for (int j = 0; j < 16; ++j)
      zrow[j] = Ya[kk][j] + ((j == kk) ? 1.f : 0.f);
    const float hs = 0.5f * sg;
    float s0 = 0.f, s1 = 0.f;
#pragma unroll
    for (int j = 0; j < 8; ++j) {
      s0 = fmaf(zrow[j], a0[8 + j], s0);     //  Z[k][j]   * av[j]
      s0 = fmaf(-zrow[8 + j], a0[j], s0);    // -Z[k][8+j] * au[j]
      s1 = fmaf(zrow[j], a1[8 + j], s1);
      s1 = fmaf(-zrow[8 + j], a1[j], s1);
    }
    const float cp0 = hs * s0, cp1 = hs * s1;
#pragma unroll
    for (int k = 0; k < 16; ++k) {
      ch0[k] = __float2half2_rn(__shfl(cp0, k, 64));
      ch1[k] = __float2half2_rn(__shfl(cp1, k, 64));
    }
  }

  // phase 2: out = x + corr; 4 independent half2 chains per row (depth 8)
  float4* o4A = (float4*)(out + (size_t)row0 * DIM);
  float4* o4B = o4A + DIM / 4;
  const __half2 hz = __float2half2_rn(0.f);
#define HF2(acc, c, w) acc = __hfma2(c, __builtin_bit_cast(__half2, w), acc)
#pragma unroll 2
  for (int i = 0; i < 8; ++i) {
    const int iq = i * 64 + lane;
    const float4 xA = x4A[iq], xB = x4B[iq];
    const uint4 A0 = uvQ[0][2 * iq], A1 = uvQ[0][2 * iq + 1];
    const uint4 B0 = uvQ[1][2 * iq], B1 = uvQ[1][2 * iq + 1];
    const uint4 C0 = uvQ[2][2 * iq], C1 = uvQ[2][2 * iq + 1];
    const uint4 D0 = uvQ[3][2 * iq], D1 = uvQ[3][2 * iq + 1];
    // row A
    __half2 tA0 = hz, tA1 = hz, tA2 = hz, tA3 = hz;
    HF2(tA0, ch0[0], A0.x);  HF2(tA0, ch0[1], A0.y);
    HF2(tA0, ch0[2], A0.z);  HF2(tA0, ch0[3], A0.w);
    HF2(tA0, ch0[4], B0.x);  HF2(tA0, ch0[5], B0.y);
    HF2(tA0, ch0[6], B0.z);  HF2(tA0, ch0[7], B0.w);
    HF2(tA1, ch0[8], C0.x);  HF2(tA1, ch0[9], C0.y);
    HF2(tA1, ch0[10], C0.z); HF2(tA1, ch0[11], C0.w);
    HF2(tA1, ch0[12], D0.x); HF2(tA1, ch0[13], D0.y);
    HF2(tA1, ch0[14], D0.z); HF2(tA1, ch0[15], D0.w);
    HF2(tA2, ch0[0], A1.x);  HF2(tA2, ch0[1], A1.y);
    HF2(tA2, ch0[2], A1.z);  HF2(tA2, ch0[3], A1.w);
    HF2(tA2, ch0[4], B1.x);  HF2(tA2, ch0[5], B1.y);
    HF2(tA2, ch0[6], B1.z);  HF2(tA2, ch0[7], B1.w);
    HF2(tA3, ch0[8], C1.x);  HF2(tA3, ch0[9], C1.y);
    HF2(tA3, ch0[10], C1.z); HF2(tA3, ch0[11], C1.w);
    HF2(tA3, ch0[12], D1.x); HF2(tA3, ch0[13], D1.y);
    HF2(tA3, ch0[14], D1.z); HF2(tA3, ch0[15], D1.w);
    // row B
    __half2 tB0 = hz, tB1 = hz, tB2 = hz, tB3 = hz;
    HF2(tB0, ch1[0], A0.x);  HF2(tB0, ch1[1], A0.y);
    HF2(tB0, ch1[2], A0.z);  HF2(tB0, ch1[3], A0.w);
    HF2(tB0, ch1[4], B0.x);  HF2(tB0, ch1[5], B0.y);
    HF2(tB0, ch1[6], B0.z);  HF2(tB0, ch1[7], B0.w);
    HF2(tB1, ch1[8], C0.x);  HF2(tB1, ch1[9], C0.y);
    HF2(tB1, ch1[10], C0.z); HF2(tB1, ch1[11], C0.w);
    HF2(tB1, ch1[12], D0.x); HF2(tB1, ch1[13], D0.y);
    HF2(tB1, ch1[14], D0.z); HF2(tB1, ch1[15], D0.w);
    HF2(tB2, ch1[0], A1.x);  HF2(tB2, ch1[1], A1.y);
    HF2(tB2, ch1[2], A1.z);  HF2(tB2, ch1[3], A1.w);
    HF2(tB2, ch1[4], B1.x);  HF2(tB2, ch1[5], B1.y);
    HF2(tB2, ch1[6], B1.z);  HF2(tB2, ch1[7], B1.w);
    HF2(tB3, ch1[8], C1.x);  HF2(tB3, ch1[9], C1.y);
    HF2(tB3, ch1[10], C1.z); HF2(tB3, ch1[11], C1.w);
    HF2(tB3, ch1[12], D1.x); HF2(tB3, ch1[13], D1.y);
    HF2(tB3, ch1[14], D1.z); HF2(tB3, ch1[15], D1.w);

    const __half2 sA0 = __hadd2(tA0, tA1), sA1 = __hadd2(tA2, tA3);
    const __half2 sB0 = __hadd2(tB0, tB1), sB1 = __hadd2(tB2, tB3);
    float4 oA, oB;
    oA.x = xA.x + __low2float(sA0);
    oA.y = xA.y + __high2float(sA0);
    oA.z = xA.z + __low2float(sA1);
    oA.w = xA.w + __high2float(sA1);
    oB.x = xB.x + __low2float(sB0);
    oB.y = xB.y + __high2float(sB0);
    oB.z = xB.z + __low2float(sB1);
    oB.w = xB.w + __high2float(sB1);
    o4A[iq] = oA;
    o4B[iq] = oB;
  }
#undef HF2
}

extern "C" void kernel_launch(void* const* d_in, const int* in_sizes, int n_in,
                              void* d_out, int out_size, void* d_ws, size_t ws_size,
                              hipStream_t stream) {
  const float* x    = (const float*)d_in[0];
  const float* U    = (const float*)d_in[1];
  const float* V    = (const float*)d_in[2];
  const float* gate = (const float*)d_in[3];
  float* out = (float*)d_out;
  float* prodw = (float*)d_ws;   // 192 floats

  rora_gram<<<192, 256, 0, stream>>>(U, V, prodw);
  rora_fused<<<NTOK / 16, 512, 0, stream>>>(x, U, V, gate, prodw, out);
}